// Round 7
// baseline (680.220 us; speedup 1.0000x reference)
//
#include <hip/hip_runtime.h>
#include <float.h>
#include <math.h>

// Problem constants (fixed by the reference)
#define NB 1024
#define HD 64
#define NSTEPS 5
#define LN 576          // LDS-cached nodes (local indices 512..1087)
#define LTILES 36       // LN/16

__device__ __forceinline__ float sigmoidf_(float x) {
    return 1.0f / (1.0f + __expf(-x));
}

// ---------------- segment boundaries from sorted batch ----------------
__global__ void seg_bounds_kernel(const int* __restrict__ batch,
                                  int* __restrict__ seg_start, int n) {
    int i = blockIdx.x * blockDim.x + threadIdx.x;
    if (i >= n) return;
    int b = batch[i];
    if (i == 0) {
        for (int j = 0; j <= b; ++j) seg_start[j] = 0;
    } else {
        int pb = batch[i - 1];
        for (int j = pb + 1; j <= b; ++j) seg_start[j] = i;
    }
    if (i == n - 1) {
        for (int j = b + 1; j <= NB; ++j) seg_start[j] = n;
    }
}

__device__ __forceinline__ void async_ld16(const float* g, float* l) {
    __builtin_amdgcn_global_load_lds(
        (const __attribute__((address_space(1))) void*)g,
        (__attribute__((address_space(3))) void*)l, 16, 0, 0);
}

__device__ __forceinline__ float dot4(float4 a, float4 b) {
    float d = a.x * b.x;
    d = fmaf(a.y, b.y, d);
    d = fmaf(a.z, b.z, d);
    return fmaf(a.w, b.w, d);
}
__device__ __forceinline__ float4 shfl_xor4(float4 v, int m) {
    return make_float4(__shfl_xor(v.x, m), __shfl_xor(v.y, m),
                       __shfl_xor(v.z, m), __shfl_xor(v.w, m));
}
__device__ __forceinline__ float4 add4(float4 a, float4 b) {
    return make_float4(a.x + b.x, a.y + b.y, a.z + b.z, a.w + b.w);
}
__device__ __forceinline__ float4 sfma4(float a, float4 v, float4 c) {
    return make_float4(fmaf(a, v.x, c.x), fmaf(a, v.y, c.y),
                       fmaf(a, v.z, c.z), fmaf(a, v.w, c.w));
}
__device__ __forceinline__ float4 smul4(float a, float4 v) {
    return make_float4(a * v.x, a * v.y, a * v.z, a * v.w);
}

// One block == one graph; LANE-OWNS-NODE (transposed) layout:
//  - nodes 0..511   (local): lane lg holds all 64 features in regs (x1[16] f4)
//  - nodes 512..1087: LDS, chunk-swizzled (slot = k ^ (node&7)) for conflict-
//    free lane-local column reads; staged once via global_load_lds with the
//    inverse (involutive) swizzle applied to the GLOBAL source address (m173).
//  - nodes >=1088 (rare tail): recomputed from global (L2-hot) each pass.
// Dot products and exp are lane-local (no per-node shuffles); softmax is exact
// two-pass (graph max M, then exp) -> no online-rescale dependency chains.
// Per-wave r-merge = one 63-shuffle butterfly per 32-feature half.
// 147 KB LDS forces 1 block/CU -> allocator budget 256 VGPR (attrs pin it).
__global__ __attribute__((amdgpu_flat_work_group_size(512, 512)))
__attribute__((amdgpu_waves_per_eu(2, 2)))
void set2set_fused_kernel(
    const float* __restrict__ x,     // [N,64]
    const int* __restrict__ seg,     // [NB+1]
    const float* __restrict__ W_ih,  // [256,128]
    const float* __restrict__ W_hh,  // [256,64]
    const float* __restrict__ b_ih,  // [256]
    const float* __restrict__ b_hh,  // [256]
    const float* __restrict__ W1,    // [256,128]
    const float* __restrict__ b1,    // [256]
    const float* __restrict__ W2,    // [128,256]
    const float* __restrict__ b2,    // [128]
    float* __restrict__ out)         // [NB,128]
{
    __shared__ __align__(16) float xl[LN * HD];   // 147456 B swizzled node cache
    __shared__ __align__(16) float hs[HD], cs[HD], rs[HD];
    __shared__ __align__(16) float gates[256], gpart[256];
    __shared__ __align__(16) float lr[8][HD];
    __shared__ float lm[8], ls[8];

    const int b = blockIdx.x;
    const int tid = threadIdx.x;
    const int lane = tid & 63;
    const int wv = tid >> 6;
    const int lg = tid;               // lane-global id 0..511 == local node id

    const int s0 = seg[b], e0 = seg[b + 1];
    const int len = e0 - s0;
    const int maxidx4 = max(e0 * 16 - 1, 0);

    // ---- register cache: node s0+lg (all 64 features in this lane) ----
    float4 x1[16];
    {
        int nd = (len > 0) ? (s0 + min(lg, len - 1)) : 0;
        const float* gp = x + (size_t)nd * 64;
#pragma unroll
        for (int k = 0; k < 16; ++k) x1[k] = *(const float4*)(gp + k * 4);
    }
    // ---- LDS cache: nodes 512..1087, chunk slot = k ^ (node&7) ----
    for (int t = wv; t < LTILES; t += 8) {
        if (512 + t * 16 >= len) break;
#pragma unroll
        for (int u = 0; u < 4; ++u) {
            int node = 512 + t * 16 + u * 4 + (lane >> 4);
            int ksrc = (lane & 15) ^ (node & 7);
            int g4 = min((s0 + node) * 16 + ksrc, maxidx4);
            async_ld16(x + (size_t)g4 * 4, xl + t * 1024 + u * 256);
        }
    }
    asm volatile("s_waitcnt vmcnt(0)" ::: "memory");
    if (tid < HD) { hs[tid] = 0.0f; cs[tid] = 0.0f; rs[tid] = 0.0f; }
    __syncthreads();

    const bool v1  = lg < len;                       // reg node valid
    const bool vl1 = (512 + lg) < len;               // LDS node A valid
    const bool vl2 = (wv == 0) && ((1024 + lane) < len);  // LDS node B (wave0)
    const int  sw1 = lg & 7;                         // swizzle of node 512+lg
    const int  sw2 = lane & 7;                       // swizzle of node 1024+lane

    for (int step = 0; step < NSTEPS; ++step) {
        // ---- LSTM cell ----
        if (step == 0) {
            if (tid < 256) gates[tid] = b_ih[tid] + b_hh[tid];
        } else {
            float acc = 0.0f;
            if (tid < 256) {
                acc = b_ih[tid] + b_hh[tid];
                const float4* w = (const float4*)(W_ih + tid * 128);
                const float4* hq = (const float4*)hs;
                const float4* rq = (const float4*)rs;
#pragma unroll
                for (int k = 0; k < 16; ++k) acc += dot4(w[k], hq[k]);
#pragma unroll
                for (int k = 0; k < 16; ++k) acc += dot4(w[16 + k], rq[k]);
            } else {
                int j = tid - 256;
                float a2 = 0.0f;
                const float4* w = (const float4*)(W_hh + j * 64);
                const float4* hq = (const float4*)hs;
#pragma unroll
                for (int k = 0; k < 16; ++k) a2 += dot4(w[k], hq[k]);
                gpart[j] = a2;
            }
            __syncthreads();
            if (tid < 256) gates[tid] = acc + gpart[tid];
        }
        __syncthreads();
        if (tid < HD) {
            float ig = sigmoidf_(gates[tid]);
            float fg = sigmoidf_(gates[tid + 64]);
            float gg = tanhf(gates[tid + 128]);
            float og = sigmoidf_(gates[tid + 192]);
            float cp = (step == 0) ? 0.0f : cs[tid];
            float cn = fmaf(fg, cp, ig * gg);
            cs[tid] = cn;
            hs[tid] = og * tanhf(cn);
        }
        __syncthreads();

        // ---- phase A: lane-local dot products, then one max reduce ----
        float d1a = 0.f, d1b = 0.f, la = 0.f, lb = 0.f;
#pragma unroll
        for (int k = 0; k < 16; ++k) {
            float4 q4 = *(const float4*)(hs + k * 4);
            float dv = dot4(x1[k], q4);
            float lv = dot4(*(const float4*)(xl + lg * 64 + ((k ^ sw1) << 2)), q4);
            if (k & 1) { d1b += dv; lb += lv; } else { d1a += dv; la += lv; }
        }
        float d2a = 0.f, d2b = 0.f;
        if (wv == 0) {
#pragma unroll
            for (int k = 0; k < 16; ++k) {
                float4 q4 = *(const float4*)(hs + k * 4);
                float lv = dot4(*(const float4*)(xl + (512 + lane) * 64 + ((k ^ sw2) << 2)), q4);
                if (k & 1) d2b += lv; else d2a += lv;
            }
        }
        float e1  = v1  ? (d1a + d1b) : -FLT_MAX;
        float el1 = vl1 ? (la + lb)   : -FLT_MAX;
        float el2 = vl2 ? (d2a + d2b) : -FLT_MAX;
        float ml = fmaxf(fmaxf(e1, el1), el2);
        for (int nb = 1088 + lg; nb < len; nb += 512) {   // rare tail
            const float* gp = x + (size_t)(s0 + nb) * 64;
            float da = 0.f, db = 0.f;
#pragma unroll
            for (int k = 0; k < 16; ++k) {
                float dv = dot4(*(const float4*)(gp + k * 4), *(const float4*)(hs + k * 4));
                if (k & 1) db += dv; else da += dv;
            }
            ml = fmaxf(ml, da + db);
        }
#pragma unroll
        for (int off = 1; off < 64; off <<= 1) ml = fmaxf(ml, __shfl_xor(ml, off));
        if (lane == 0) lm[wv] = ml;
        __syncthreads();
        float M = lm[0];
#pragma unroll
        for (int w = 1; w < 8; ++w) M = fmaxf(M, lm[w]);

        float a1  = v1  ? __expf(e1 - M)  : 0.f;
        float al1 = vl1 ? __expf(el1 - M) : 0.f;
        float al2 = vl2 ? __expf(el2 - M) : 0.f;
        float s_lane = a1 + al1 + al2;
        for (int nb = 1088 + lg; nb < len; nb += 512) {   // rare tail: a into sum
            const float* gp = x + (size_t)(s0 + nb) * 64;
            float da = 0.f, db = 0.f;
#pragma unroll
            for (int k = 0; k < 16; ++k) {
                float dv = dot4(*(const float4*)(gp + k * 4), *(const float4*)(hs + k * 4));
                if (k & 1) db += dv; else da += dv;
            }
            s_lane += __expf(da + db - M);
        }
        float sw_ = s_lane;
#pragma unroll
        for (int off = 1; off < 64; off <<= 1) sw_ += __shfl_xor(sw_, off);
        if (lane == 0) ls[wv] = sw_;

        // ---- phase B: per-lane weighted sums, butterfly per 32-feature half ----
#pragma unroll
        for (int h = 0; h < 2; ++h) {
            float4 r8[8];
#pragma unroll
            for (int j = 0; j < 8; ++j) r8[j] = smul4(a1, x1[h * 8 + j]);
#pragma unroll
            for (int j = 0; j < 8; ++j) {
                int k = h * 8 + j;
                float4 lv = *(const float4*)(xl + lg * 64 + ((k ^ sw1) << 2));
                r8[j] = sfma4(al1, lv, r8[j]);
            }
            if (wv == 0) {
#pragma unroll
                for (int j = 0; j < 8; ++j) {
                    int k = h * 8 + j;
                    float4 lv = *(const float4*)(xl + (512 + lane) * 64 + ((k ^ sw2) << 2));
                    r8[j] = sfma4(al2, lv, r8[j]);
                }
            }
            for (int nb = 1088 + lg; nb < len; nb += 512) {   // rare tail
                const float* gp = x + (size_t)(s0 + nb) * 64;
                float da = 0.f, db = 0.f;
#pragma unroll
                for (int k = 0; k < 16; ++k) {
                    float dv = dot4(*(const float4*)(gp + k * 4), *(const float4*)(hs + k * 4));
                    if (k & 1) db += dv; else da += dv;
                }
                float a = __expf(da + db - M);
#pragma unroll
                for (int j = 0; j < 8; ++j)
                    r8[j] = sfma4(a, *(const float4*)(gp + (h * 8 + j) * 4), r8[j]);
            }
            // butterfly: 64 lanes x 32 floats -> feature (lane>>1)&31
            {
                bool s = lane & 32;
#pragma unroll
                for (int j = 0; j < 4; ++j) {
                    float4 kp = s ? r8[j + 4] : r8[j];
                    float4 sd = s ? r8[j] : r8[j + 4];
                    r8[j] = add4(kp, shfl_xor4(sd, 32));
                }
            }
            {
                bool s = lane & 16;
#pragma unroll
                for (int j = 0; j < 2; ++j) {
                    float4 kp = s ? r8[j + 2] : r8[j];
                    float4 sd = s ? r8[j] : r8[j + 2];
                    r8[j] = add4(kp, shfl_xor4(sd, 16));
                }
            }
            {
                bool s = lane & 8;
                float4 kp = s ? r8[1] : r8[0];
                float4 sd = s ? r8[0] : r8[1];
                r8[0] = add4(kp, shfl_xor4(sd, 8));
            }
            float p0, p1;
            {
                bool s = lane & 4;
                p0 = s ? r8[0].z : r8[0].x;
                p1 = s ? r8[0].w : r8[0].y;
                float q0 = s ? r8[0].x : r8[0].z;
                float q1 = s ? r8[0].y : r8[0].w;
                p0 += __shfl_xor(q0, 4);
                p1 += __shfl_xor(q1, 4);
            }
            float pv;
            {
                bool s = lane & 2;
                pv = s ? p1 : p0;
                float sd = s ? p0 : p1;
                pv += __shfl_xor(sd, 2);
            }
            pv += __shfl_xor(pv, 1);
            if (!(lane & 1)) lr[wv][h * 32 + ((lane >> 1) & 31)] = pv;
        }
        __syncthreads();

        if (tid < HD) {
            float S = 0.f, rf = 0.f;
#pragma unroll
            for (int w = 0; w < 8; ++w) { S += ls[w]; rf += lr[w][tid]; }
            rs[tid] = rf / fmaxf(S, 1e-16f);
        }
        __syncthreads();
    }

    // ---- MLP head: out = relu([h|r] @ W1^T + b1) @ W2^T + b2 ----
    if (tid < 256) {
        float acc = b1[tid];
        const float4* w = (const float4*)(W1 + tid * 128);
        const float4* hq = (const float4*)hs;
        const float4* rq = (const float4*)rs;
#pragma unroll
        for (int k = 0; k < 16; ++k) acc += dot4(w[k], hq[k]);
#pragma unroll
        for (int k = 0; k < 16; ++k) acc += dot4(w[16 + k], rq[k]);
        gates[tid] = fmaxf(acc, 0.0f);
    }
    __syncthreads();
    if (tid < 128) {
        float acc = b2[tid];
        const float4* w = (const float4*)(W2 + tid * 256);
        const float4* hq = (const float4*)gates;
#pragma unroll 8
        for (int k = 0; k < 64; ++k) acc += dot4(w[k], hq[k]);
        out[b * 128 + tid] = acc;
    }
}

extern "C" void kernel_launch(void* const* d_in, const int* in_sizes, int n_in,
                              void* d_out, int out_size, void* d_ws, size_t ws_size,
                              hipStream_t stream) {
    const float* x     = (const float*)d_in[0];
    const int*   batch = (const int*)d_in[1];
    const float* W_ih  = (const float*)d_in[2];
    const float* W_hh  = (const float*)d_in[3];
    const float* b_ih  = (const float*)d_in[4];
    const float* b_hh  = (const float*)d_in[5];
    const float* W1    = (const float*)d_in[6];
    const float* b1    = (const float*)d_in[7];
    const float* W2    = (const float*)d_in[8];
    const float* b2    = (const float*)d_in[9];
    float* out = (float*)d_out;
    const int N = in_sizes[1];

    int* seg = (int*)d_ws;

    seg_bounds_kernel<<<(N + 255) / 256, 256, 0, stream>>>(batch, seg, N);
    set2set_fused_kernel<<<NB, 512, 0, stream>>>(x, seg, W_ih, W_hh, b_ih, b_hh,
                                                 W1, b1, W2, b2, out);
}

// Round 8
// 574.619 us; speedup vs baseline: 1.1838x; 1.1838x over previous
//
#include <hip/hip_runtime.h>
#include <float.h>
#include <math.h>

// Problem constants (fixed by the reference)
#define NB 1024      // number of graphs B
#define HD 64        // feature dim H
#define NSTEPS 5
#define LT 16        // LDS-cached tiles (16 nodes each): nodes 0..255, 64 KB
#define RT2 4        // register-cached tiles per wave: tiles LT..LT+31 (nodes 256..767)

__device__ __forceinline__ float sigmoidf_(float x) {
    return 1.0f / (1.0f + __expf(-x));
}

// ---------------- segment boundaries from sorted batch ----------------
__global__ void seg_bounds_kernel(const int* __restrict__ batch,
                                  int* __restrict__ seg_start, int n) {
    int i = blockIdx.x * blockDim.x + threadIdx.x;
    if (i >= n) return;
    int b = batch[i];
    if (i == 0) {
        for (int j = 0; j <= b; ++j) seg_start[j] = 0;
    } else {
        int pb = batch[i - 1];
        for (int j = pb + 1; j <= b; ++j) seg_start[j] = i;
    }
    if (i == n - 1) {
        for (int j = b + 1; j <= NB; ++j) seg_start[j] = n;
    }
}

// async 16B/lane global->LDS: LDS base wave-uniform (HW adds lane*16),
// global source address is per-lane.
__device__ __forceinline__ void async_ld16(const float* g, float* l) {
    __builtin_amdgcn_global_load_lds(
        (const __attribute__((address_space(1))) void*)g,
        (__attribute__((address_space(3))) void*)l, 16, 0, 0);
}

// Online-softmax update for accumulator set U with value XV (float4 of 4 features)
// of node NODE (segment-local index). mm/ss/rr are static-indexed register arrays.
#define ONLINE_UPD(U, XV, NODE)                                         \
    {                                                                   \
        float d = (XV).x * q4.x;                                        \
        d = fmaf((XV).y, q4.y, d);                                      \
        d = fmaf((XV).z, q4.z, d);                                      \
        d = fmaf((XV).w, q4.w, d);                                      \
        d += __shfl_xor(d, 1);                                          \
        d += __shfl_xor(d, 2);                                          \
        d += __shfl_xor(d, 4);                                          \
        d += __shfl_xor(d, 8);                                          \
        bool valid = (NODE) < len;                                      \
        float eeff = valid ? d : -FLT_MAX;                              \
        float nm = fmaxf(mm[U], eeff);                                  \
        float sc = __expf(mm[U] - nm);                                  \
        float w = valid ? __expf(eeff - nm) : 0.0f;                     \
        ss[U] = fmaf(ss[U], sc, w);                                     \
        rr[U].x = fmaf(rr[U].x, sc, w * (XV).x);                        \
        rr[U].y = fmaf(rr[U].y, sc, w * (XV).y);                        \
        rr[U].z = fmaf(rr[U].z, sc, w * (XV).z);                        \
        rr[U].w = fmaf(rr[U].w, sc, w * (XV).w);                        \
        mm[U] = nm;                                                     \
    }

// One block == one graph. Hybrid on-chip cache, sized for 2 BLOCKS/CU
// (~70 KB LDS, VGPR<=128) -> 4 waves/SIMD and half the sequential rounds
// vs the 149 KB variant (R6: 1 block/CU, 2 waves/SIMD, latency-bound at
// VALUBusy 25%).
//   - LDS:       tiles 0..LT-1   (256 nodes, 64 KB) via global_load_lds
//   - registers: tiles LT..LT+31 (512 nodes, 64 VGPR/lane)
//   - tail nodes >=768: streamed per step; per-block tail ~52 KB stays
//     L2-resident across steps (32 CU x 2 blocks x 52 KB < 4 MB/XCD).
__global__ __attribute__((amdgpu_flat_work_group_size(512, 512)))
void set2set_fused_kernel(
    const float* __restrict__ x,     // [N,64]
    const int* __restrict__ seg,     // [NB+1]
    const float* __restrict__ W_ih,  // [256,128]
    const float* __restrict__ W_hh,  // [256,64]
    const float* __restrict__ b_ih,  // [256]
    const float* __restrict__ b_hh,  // [256]
    const float* __restrict__ W1,    // [256,128]
    const float* __restrict__ b1,    // [256]
    const float* __restrict__ W2,    // [128,256]
    const float* __restrict__ b2,    // [128]
    float* __restrict__ out)         // [NB,128]
{
    __shared__ __align__(16) float xl[LT * 16 * HD];   // 64 KB node cache
    __shared__ __align__(16) float hs[HD], cs[HD], rs[HD];
    __shared__ __align__(16) float gates[256], gpart[256];
    __shared__ __align__(16) float lr[8][HD];
    __shared__ float lm[8], ls[8];

    const int b = blockIdx.x;
    const int tid = threadIdx.x;
    const int lane = tid & 63;
    const int wv = tid >> 6;           // wave 0..7
    const int fc = lane & 15;          // feature chunk (4 floats)
    const int grp = lane >> 4;         // node subgroup 0..3

    const int s0 = seg[b], e0 = seg[b + 1];
    const int len = e0 - s0;
    const int ntiles = (len + 15) >> 4;          // 16-node tiles
    const int maxidx4 = max(e0 * 16 - 1, 0);     // clamp (global float4 index)
    const int ltiles = min(LT, ntiles);          // tiles resident in LDS

    // ---- register cache: tiles LT + wv + 8*j ----
    // Lane l of slot (j,u) holds features [fc*4,fc*4+4) of node-local (u*4+grp).
    float4 xr[4 * RT2];
#pragma unroll
    for (int j = 0; j < RT2; ++j) {
        int t = LT + wv + 8 * j;
        if (t < ntiles) {
            int tb4 = (s0 + t * 16) * 16;
#pragma unroll
            for (int u = 0; u < 4; ++u) {
                int g4 = min(tb4 + u * 64 + lane, maxidx4);
                xr[4 * j + u] = *(const float4*)(x + (size_t)g4 * 4);
            }
        }
    }
    // ---- LDS cache: tiles wv, wv+8 (< ltiles), via async global->LDS DMA ----
    // Tile t occupies xl[t*1024 .. t*1024+1024): node-major, 64 floats/node --
    // exactly the linear lane-order global_load_lds writes (dst + lane*16B).
    for (int t = wv; t < ltiles; t += 8) {
        int tb4 = (s0 + t * 16) * 16;
        float* dst = xl + t * 1024;
#pragma unroll
        for (int u = 0; u < 4; ++u) {
            int g4 = min(tb4 + u * 64 + lane, maxidx4);
            async_ld16(x + (size_t)g4 * 4, dst + u * 256);
        }
    }
    asm volatile("s_waitcnt vmcnt(0)" ::: "memory");

    if (tid < HD) { hs[tid] = 0.0f; cs[tid] = 0.0f; rs[tid] = 0.0f; }
    __syncthreads();

    for (int step = 0; step < NSTEPS; ++step) {
        // ---- LSTM cell: gates = W_ih*[h|r] + W_hh*h + biases ----
        if (step == 0) {
            // q_star = h = 0 -> gates are pure bias
            if (tid < 256) gates[tid] = b_ih[tid] + b_hh[tid];
        } else {
            float acc = 0.0f;
            if (tid < 256) {
                acc = b_ih[tid] + b_hh[tid];
                const float4* w = (const float4*)(W_ih + tid * 128);
                const float4* hq = (const float4*)hs;
                const float4* rq = (const float4*)rs;
#pragma unroll
                for (int k = 0; k < 16; ++k) {
                    float4 ww = w[k]; float4 v = hq[k];
                    acc = fmaf(ww.x, v.x, acc); acc = fmaf(ww.y, v.y, acc);
                    acc = fmaf(ww.z, v.z, acc); acc = fmaf(ww.w, v.w, acc);
                }
#pragma unroll
                for (int k = 0; k < 16; ++k) {
                    float4 ww = w[16 + k]; float4 v = rq[k];
                    acc = fmaf(ww.x, v.x, acc); acc = fmaf(ww.y, v.y, acc);
                    acc = fmaf(ww.z, v.z, acc); acc = fmaf(ww.w, v.w, acc);
                }
            } else {
                int j = tid - 256;
                float a2 = 0.0f;
                const float4* w = (const float4*)(W_hh + j * 64);
                const float4* hq = (const float4*)hs;
#pragma unroll
                for (int k = 0; k < 16; ++k) {
                    float4 ww = w[k]; float4 v = hq[k];
                    a2 = fmaf(ww.x, v.x, a2); a2 = fmaf(ww.y, v.y, a2);
                    a2 = fmaf(ww.z, v.z, a2); a2 = fmaf(ww.w, v.w, a2);
                }
                gpart[j] = a2;
            }
            __syncthreads();
            if (tid < 256) gates[tid] = acc + gpart[tid];
        }
        __syncthreads();

        if (tid < HD) {
            float ig = sigmoidf_(gates[tid]);
            float fg = sigmoidf_(gates[tid + 64]);
            float gg = tanhf(gates[tid + 128]);
            float og = sigmoidf_(gates[tid + 192]);
            float cp = (step == 0) ? 0.0f : cs[tid];
            float cn = fmaf(fg, cp, ig * gg);
            cs[tid] = cn;
            hs[tid] = og * tanhf(cn);
        }
        __syncthreads();

        // ---- attention over this graph's nodes (q = h), from LDS + regs + L2 tail ----
        float4 q4 = *(const float4*)(hs + fc * 4);
        float mm[4], ss[4];
        float4 rr[4];
#pragma unroll
        for (int u = 0; u < 4; ++u) {
            mm[u] = -FLT_MAX; ss[u] = 0.0f;
            rr[u] = make_float4(0.0f, 0.0f, 0.0f, 0.0f);
        }

        // LDS-cached tiles (disjoint per wave)
        for (int t = wv; t < ltiles; t += 8) {
            const float* bt = xl + t * 1024;
            int nbase = t * 16;
#pragma unroll
            for (int u = 0; u < 4; ++u) {
                float4 xv = *(const float4*)(bt + u * 256 + grp * 64 + fc * 4);
                ONLINE_UPD(u, xv, nbase + u * 4 + grp);
            }
        }
        // register-cached tiles
#pragma unroll
        for (int j = 0; j < RT2; ++j) {
            int t = LT + wv + 8 * j;
            if (t < ntiles) {
                int nbase = t * 16;
                ONLINE_UPD(0, xr[4 * j + 0], nbase + 0 * 4 + grp);
                ONLINE_UPD(1, xr[4 * j + 1], nbase + 1 * 4 + grp);
                ONLINE_UPD(2, xr[4 * j + 2], nbase + 2 * 4 + grp);
                ONLINE_UPD(3, xr[4 * j + 3], nbase + 3 * 4 + grp);
            }
        }
        // tail tiles beyond both caches: stream from global (L2-resident after
        // first touch -- per-block tail slice ~52 KB)
        for (int t = LT + 8 * RT2 + wv; t < ntiles; t += 8) {
            int tb4 = (s0 + t * 16) * 16;
            int nbase = t * 16;
#pragma unroll
            for (int u = 0; u < 4; ++u) {
                int g4 = min(tb4 + u * 64 + lane, maxidx4);
                float4 xv = *(const float4*)(x + (size_t)g4 * 4);
                ONLINE_UPD(u, xv, nbase + u * 4 + grp);
            }
        }

        // merge the 4 accumulator sets within the lane
        float m = mm[0], sum = ss[0];
        float4 r4 = rr[0];
#pragma unroll
        for (int u = 1; u < 4; ++u) {
            float nm = fmaxf(m, mm[u]);
            float s1 = __expf(m - nm);
            float s2 = __expf(mm[u] - nm);
            sum = sum * s1 + ss[u] * s2;
            r4.x = r4.x * s1 + rr[u].x * s2;
            r4.y = r4.y * s1 + rr[u].y * s2;
            r4.z = r4.z * s1 + rr[u].z * s2;
            r4.w = r4.w * s1 + rr[u].w * s2;
            m = nm;
        }
        // merge the 4 node-subgroups within the wave (lanes with equal fc)
#pragma unroll
        for (int off = 16; off < 64; off <<= 1) {
            float om = __shfl_xor(m, off);
            float os = __shfl_xor(sum, off);
            float ox = __shfl_xor(r4.x, off);
            float oy = __shfl_xor(r4.y, off);
            float oz = __shfl_xor(r4.z, off);
            float ow = __shfl_xor(r4.w, off);
            float nm = fmaxf(m, om);
            float s1 = __expf(m - nm);
            float s2 = __expf(om - nm);
            sum = sum * s1 + os * s2;
            r4.x = r4.x * s1 + ox * s2;
            r4.y = r4.y * s1 + oy * s2;
            r4.z = r4.z * s1 + oz * s2;
            r4.w = r4.w * s1 + ow * s2;
            m = nm;
        }
        if (lane < 16) {
            if (lane == 0) { lm[wv] = m; ls[wv] = sum; }
            *(float4*)&lr[wv][lane * 4] = r4;
        }
        __syncthreads();

        // merge 8 wave partials -> normalized r (stays in LDS)
        if (tid < HD) {
            float M = lm[0];
#pragma unroll
            for (int w = 1; w < 8; ++w) M = fmaxf(M, lm[w]);
            float S = 0.0f, rf = 0.0f;
#pragma unroll
            for (int w = 0; w < 8; ++w) {
                float ww = __expf(lm[w] - M);
                S = fmaf(ls[w], ww, S);
                rf = fmaf(lr[w][tid], ww, rf);
            }
            rs[tid] = rf / fmaxf(S, 1e-16f);
        }
        __syncthreads();
    }

    // ---- MLP head: out = relu([h|r] @ W1^T + b1) @ W2^T + b2 ----
    if (tid < 256) {
        float acc = b1[tid];
        const float4* w = (const float4*)(W1 + tid * 128);
        const float4* hq = (const float4*)hs;
        const float4* rq = (const float4*)rs;
#pragma unroll
        for (int k = 0; k < 16; ++k) {
            float4 ww = w[k]; float4 v = hq[k];
            acc = fmaf(ww.x, v.x, acc); acc = fmaf(ww.y, v.y, acc);
            acc = fmaf(ww.z, v.z, acc); acc = fmaf(ww.w, v.w, acc);
        }
#pragma unroll
        for (int k = 0; k < 16; ++k) {
            float4 ww = w[16 + k]; float4 v = rq[k];
            acc = fmaf(ww.x, v.x, acc); acc = fmaf(ww.y, v.y, acc);
            acc = fmaf(ww.z, v.z, acc); acc = fmaf(ww.w, v.w, acc);
        }
        gates[tid] = fmaxf(acc, 0.0f);   // reuse as hidden activations
    }
    __syncthreads();
    if (tid < 128) {
        float acc = b2[tid];
        const float4* w = (const float4*)(W2 + tid * 256);
        const float4* hq = (const float4*)gates;
#pragma unroll 8
        for (int k = 0; k < 64; ++k) {
            float4 ww = w[k]; float4 v = hq[k];
            acc = fmaf(ww.x, v.x, acc); acc = fmaf(ww.y, v.y, acc);
            acc = fmaf(ww.z, v.z, acc); acc = fmaf(ww.w, v.w, acc);
        }
        out[b * 128 + tid] = acc;
    }
}

extern "C" void kernel_launch(void* const* d_in, const int* in_sizes, int n_in,
                              void* d_out, int out_size, void* d_ws, size_t ws_size,
                              hipStream_t stream) {
    const float* x     = (const float*)d_in[0];   // [N,64]
    const int*   batch = (const int*)d_in[1];     // [N] sorted
    const float* W_ih  = (const float*)d_in[2];   // [256,128]
    const float* W_hh  = (const float*)d_in[3];   // [256,64]
    const float* b_ih  = (const float*)d_in[4];
    const float* b_hh  = (const float*)d_in[5];
    const float* W1    = (const float*)d_in[6];   // [256,128]
    const float* b1    = (const float*)d_in[7];
    const float* W2    = (const float*)d_in[8];   // [128,256]
    const float* b2    = (const float*)d_in[9];
    float* out = (float*)d_out;
    const int N = in_sizes[1];

    int* seg = (int*)d_ws;   // NB+1 ints

    seg_bounds_kernel<<<(N + 255) / 256, 256, 0, stream>>>(batch, seg, N);
    set2set_fused_kernel<<<NB, 512, 0, stream>>>(x, seg, W_ih, W_hh, b_ih, b_hh,
                                                 W1, b1, W2, b2, out);
}

// Round 10
// 562.398 us; speedup vs baseline: 1.2095x; 1.0217x over previous
//
#include <hip/hip_runtime.h>
#include <float.h>
#include <math.h>

// Problem constants (fixed by the reference)
#define NB 1024      // number of graphs B
#define HD 64        // feature dim H
#define NSTEPS 5
#define LT 14        // LDS-cached tiles (16 nodes each): nodes 0..223, 56 KB
#define RT2 4        // register-cached tiles per wave: tiles LT..LT+31 (nodes 224..735)

__device__ __forceinline__ float sigmoidf_(float x) {
    return 1.0f / (1.0f + __expf(-x));
}

// ---------------- segment boundaries from sorted batch ----------------
__global__ void seg_bounds_kernel(const int* __restrict__ batch,
                                  int* __restrict__ seg_start, int n) {
    int i = blockIdx.x * blockDim.x + threadIdx.x;
    if (i >= n) return;
    int b = batch[i];
    if (i == 0) {
        for (int j = 0; j <= b; ++j) seg_start[j] = 0;
    } else {
        int pb = batch[i - 1];
        for (int j = pb + 1; j <= b; ++j) seg_start[j] = i;
    }
    if (i == n - 1) {
        for (int j = b + 1; j <= NB; ++j) seg_start[j] = n;
    }
}

// async 16B/lane global->LDS: LDS base wave-uniform (HW adds lane*16),
// global source address is per-lane.
__device__ __forceinline__ void async_ld16(const float* g, float* l) {
    __builtin_amdgcn_global_load_lds(
        (const __attribute__((address_space(1))) void*)g,
        (__attribute__((address_space(3))) void*)l, 16, 0, 0);
}

// Online-softmax update for accumulator set U with value XV (float4 of 4 features)
// of node NODE (segment-local index). mm/ss/rr are static-indexed register arrays.
#define ONLINE_UPD(U, XV, NODE)                                         \
    {                                                                   \
        float d = (XV).x * q4.x;                                        \
        d = fmaf((XV).y, q4.y, d);                                      \
        d = fmaf((XV).z, q4.z, d);                                      \
        d = fmaf((XV).w, q4.w, d);                                      \
        d += __shfl_xor(d, 1);                                          \
        d += __shfl_xor(d, 2);                                          \
        d += __shfl_xor(d, 4);                                          \
        d += __shfl_xor(d, 8);                                          \
        bool valid = (NODE) < len;                                      \
        float eeff = valid ? d : -FLT_MAX;                              \
        float nm = fmaxf(mm[U], eeff);                                  \
        float sc = __expf(mm[U] - nm);                                  \
        float w = valid ? __expf(eeff - nm) : 0.0f;                     \
        ss[U] = fmaf(ss[U], sc, w);                                     \
        rr[U].x = fmaf(rr[U].x, sc, w * (XV).x);                        \
        rr[U].y = fmaf(rr[U].y, sc, w * (XV).y);                        \
        rr[U].z = fmaf(rr[U].z, sc, w * (XV).z);                        \
        rr[U].w = fmaf(rr[U].w, sc, w * (XV).w);                        \
        mm[U] = nm;                                                     \
    }

// One block == one graph. Hybrid on-chip cache, sized for 2 BLOCKS/CU.
// KEY HYPOTHESIS (from R6/R8): LDS beyond 64 KB is single-workgroup-only on
// gfx950 -- R8's 69 KB still got 1 block/CU (Occupancy 22.6%, dur 324 ~= R6's
// 334 at 149 KB). This version keeps TOTAL LDS = 62.3 KB < 64 KB so two
// 8-wave blocks can co-reside -> 16 waves/CU, 2 dispatch rounds instead of 4,
// 2x the latency hiding for the shuffle/exp dependency chains that dominate
// (R1-R8 invariant ~310-334 us regardless of memory strategy).
//   - LDS:       tiles 0..LT-1   (224 nodes, 56 KB) via global_load_lds
//   - registers: tiles LT..LT+31 (512 nodes, 64 VGPR/lane)
//   - tail nodes >=736: streamed per step; L2-resident after first touch
//     (R8 measured this tail as ~free: per-round time unchanged).
__global__ __attribute__((amdgpu_flat_work_group_size(512, 512)))
void set2set_fused_kernel(
    const float* __restrict__ x,     // [N,64]
    const int* __restrict__ seg,     // [NB+1]
    const float* __restrict__ W_ih,  // [256,128]
    const float* __restrict__ W_hh,  // [256,64]
    const float* __restrict__ b_ih,  // [256]
    const float* __restrict__ b_hh,  // [256]
    const float* __restrict__ W1,    // [256,128]
    const float* __restrict__ b1,    // [256]
    const float* __restrict__ W2,    // [128,256]
    const float* __restrict__ b2,    // [128]
    float* __restrict__ out)         // [NB,128]
{
    __shared__ __align__(16) float xl[LT * 16 * HD];   // 56 KB node cache
    __shared__ __align__(16) float hs[HD], cs[HD], rs[HD];
    __shared__ __align__(16) float gates[256], gpart[256];
    __shared__ __align__(16) float lr[8][HD];
    __shared__ float lm[8], ls[8];

    const int b = blockIdx.x;
    const int tid = threadIdx.x;
    const int lane = tid & 63;
    const int wv = tid >> 6;           // wave 0..7
    const int fc = lane & 15;          // feature chunk (4 floats)
    const int grp = lane >> 4;         // node subgroup 0..3

    const int s0 = seg[b], e0 = seg[b + 1];
    const int len = e0 - s0;
    const int ntiles = (len + 15) >> 4;          // 16-node tiles
    const int maxidx4 = max(e0 * 16 - 1, 0);     // clamp (global float4 index)
    const int ltiles = min(LT, ntiles);          // tiles resident in LDS

    // ---- register cache: tiles LT + wv + 8*j ----
    // Lane l of slot (j,u) holds features [fc*4,fc*4+4) of node-local (u*4+grp).
    float4 xr[4 * RT2];
#pragma unroll
    for (int j = 0; j < RT2; ++j) {
        int t = LT + wv + 8 * j;
        if (t < ntiles) {
            int tb4 = (s0 + t * 16) * 16;
#pragma unroll
            for (int u = 0; u < 4; ++u) {
                int g4 = min(tb4 + u * 64 + lane, maxidx4);
                xr[4 * j + u] = *(const float4*)(x + (size_t)g4 * 4);
            }
        }
    }
    // ---- LDS cache: tiles wv, wv+8 (< ltiles), via async global->LDS DMA ----
    // Tile t occupies xl[t*1024 .. t*1024+1024): node-major, 64 floats/node --
    // exactly the linear lane-order global_load_lds writes (dst + lane*16B).
    for (int t = wv; t < ltiles; t += 8) {
        int tb4 = (s0 + t * 16) * 16;
        float* dst = xl + t * 1024;
#pragma unroll
        for (int u = 0; u < 4; ++u) {
            int g4 = min(tb4 + u * 64 + lane, maxidx4);
            async_ld16(x + (size_t)g4 * 4, dst + u * 256);
        }
    }
    asm volatile("s_waitcnt vmcnt(0)" ::: "memory");

    if (tid < HD) { hs[tid] = 0.0f; cs[tid] = 0.0f; rs[tid] = 0.0f; }
    __syncthreads();

    for (int step = 0; step < NSTEPS; ++step) {
        // ---- LSTM cell: gates = W_ih*[h|r] + W_hh*h + biases ----
        if (step == 0) {
            // q_star = h = 0 -> gates are pure bias
            if (tid < 256) gates[tid] = b_ih[tid] + b_hh[tid];
        } else {
            float acc = 0.0f;
            if (tid < 256) {
                acc = b_ih[tid] + b_hh[tid];
                const float4* w = (const float4*)(W_ih + tid * 128);
                const float4* hq = (const float4*)hs;
                const float4* rq = (const float4*)rs;
#pragma unroll
                for (int k = 0; k < 16; ++k) {
                    float4 ww = w[k]; float4 v = hq[k];
                    acc = fmaf(ww.x, v.x, acc); acc = fmaf(ww.y, v.y, acc);
                    acc = fmaf(ww.z, v.z, acc); acc = fmaf(ww.w, v.w, acc);
                }
#pragma unroll
                for (int k = 0; k < 16; ++k) {
                    float4 ww = w[16 + k]; float4 v = rq[k];
                    acc = fmaf(ww.x, v.x, acc); acc = fmaf(ww.y, v.y, acc);
                    acc = fmaf(ww.z, v.z, acc); acc = fmaf(ww.w, v.w, acc);
                }
            } else {
                int j = tid - 256;
                float a2 = 0.0f;
                const float4* w = (const float4*)(W_hh + j * 64);
                const float4* hq = (const float4*)hs;
#pragma unroll
                for (int k = 0; k < 16; ++k) {
                    float4 ww = w[k]; float4 v = hq[k];
                    a2 = fmaf(ww.x, v.x, a2); a2 = fmaf(ww.y, v.y, a2);
                    a2 = fmaf(ww.z, v.z, a2); a2 = fmaf(ww.w, v.w, a2);
                }
                gpart[j] = a2;
            }
            __syncthreads();
            if (tid < 256) gates[tid] = acc + gpart[tid];
        }
        __syncthreads();

        if (tid < HD) {
            float ig = sigmoidf_(gates[tid]);
            float fg = sigmoidf_(gates[tid + 64]);
            float gg = tanhf(gates[tid + 128]);
            float og = sigmoidf_(gates[tid + 192]);
            float cp = (step == 0) ? 0.0f : cs[tid];
            float cn = fmaf(fg, cp, ig * gg);
            cs[tid] = cn;
            hs[tid] = og * tanhf(cn);
        }
        __syncthreads();

        // ---- attention over this graph's nodes (q = h), from LDS + regs + L2 tail ----
        float4 q4 = *(const float4*)(hs + fc * 4);
        float mm[4], ss[4];
        float4 rr[4];
#pragma unroll
        for (int u = 0; u < 4; ++u) {
            mm[u] = -FLT_MAX; ss[u] = 0.0f;
            rr[u] = make_float4(0.0f, 0.0f, 0.0f, 0.0f);
        }

        // LDS-cached tiles (disjoint per wave)
        for (int t = wv; t < ltiles; t += 8) {
            const float* bt = xl + t * 1024;
            int nbase = t * 16;
#pragma unroll
            for (int u = 0; u < 4; ++u) {
                float4 xv = *(const float4*)(bt + u * 256 + grp * 64 + fc * 4);
                ONLINE_UPD(u, xv, nbase + u * 4 + grp);
            }
        }
        // register-cached tiles
#pragma unroll
        for (int j = 0; j < RT2; ++j) {
            int t = LT + wv + 8 * j;
            if (t < ntiles) {
                int nbase = t * 16;
                ONLINE_UPD(0, xr[4 * j + 0], nbase + 0 * 4 + grp);
                ONLINE_UPD(1, xr[4 * j + 1], nbase + 1 * 4 + grp);
                ONLINE_UPD(2, xr[4 * j + 2], nbase + 2 * 4 + grp);
                ONLINE_UPD(3, xr[4 * j + 3], nbase + 3 * 4 + grp);
            }
        }
        // tail tiles beyond both caches: stream from global (L2-resident after
        // first touch -- R8 measured this as ~free)
        for (int t = LT + 8 * RT2 + wv; t < ntiles; t += 8) {
            int tb4 = (s0 + t * 16) * 16;
            int nbase = t * 16;
#pragma unroll
            for (int u = 0; u < 4; ++u) {
                int g4 = min(tb4 + u * 64 + lane, maxidx4);
                float4 xv = *(const float4*)(x + (size_t)g4 * 4);
                ONLINE_UPD(u, xv, nbase + u * 4 + grp);
            }
        }

        // merge the 4 accumulator sets within the lane
        float m = mm[0], sum = ss[0];
        float4 r4 = rr[0];
#pragma unroll
        for (int u = 1; u < 4; ++u) {
            float nm = fmaxf(m, mm[u]);
            float s1 = __expf(m - nm);
            float s2 = __expf(mm[u] - nm);
            sum = sum * s1 + ss[u] * s2;
            r4.x = r4.x * s1 + rr[u].x * s2;
            r4.y = r4.y * s1 + rr[u].y * s2;
            r4.z = r4.z * s1 + rr[u].z * s2;
            r4.w = r4.w * s1 + rr[u].w * s2;
            m = nm;
        }
        // merge the 4 node-subgroups within the wave (lanes with equal fc)
#pragma unroll
        for (int off = 16; off < 64; off <<= 1) {
            float om = __shfl_xor(m, off);
            float os = __shfl_xor(sum, off);
            float ox = __shfl_xor(r4.x, off);
            float oy = __shfl_xor(r4.y, off);
            float oz = __shfl_xor(r4.z, off);
            float ow = __shfl_xor(r4.w, off);
            float nm = fmaxf(m, om);
            float s1 = __expf(m - nm);
            float s2 = __expf(om - nm);
            sum = sum * s1 + os * s2;
            r4.x = r4.x * s1 + ox * s2;
            r4.y = r4.y * s1 + oy * s2;
            r4.z = r4.z * s1 + oz * s2;
            r4.w = r4.w * s1 + ow * s2;
            m = nm;
        }
        if (lane < 16) {
            if (lane == 0) { lm[wv] = m; ls[wv] = sum; }
            *(float4*)&lr[wv][lane * 4] = r4;
        }
        __syncthreads();

        // merge 8 wave partials -> normalized r (stays in LDS)
        if (tid < HD) {
            float M = lm[0];
#pragma unroll
            for (int w = 1; w < 8; ++w) M = fmaxf(M, lm[w]);
            float S = 0.0f, rf = 0.0f;
#pragma unroll
            for (int w = 0; w < 8; ++w) {
                float ww = __expf(lm[w] - M);
                S = fmaf(ls[w], ww, S);
                rf = fmaf(lr[w][tid], ww, rf);
            }
            rs[tid] = rf / fmaxf(S, 1e-16f);
        }
        __syncthreads();
    }

    // ---- MLP head: out = relu([h|r] @ W1^T + b1) @ W2^T + b2 ----
    if (tid < 256) {
        float acc = b1[tid];
        const float4* w = (const float4*)(W1 + tid * 128);
        const float4* hq = (const float4*)hs;
        const float4* rq = (const float4*)rs;
#pragma unroll
        for (int k = 0; k < 16; ++k) {
            float4 ww = w[k]; float4 v = hq[k];
            acc = fmaf(ww.x, v.x, acc); acc = fmaf(ww.y, v.y, acc);
            acc = fmaf(ww.z, v.z, acc); acc = fmaf(ww.w, v.w, acc);
        }
#pragma unroll
        for (int k = 0; k < 16; ++k) {
            float4 ww = w[16 + k]; float4 v = rq[k];
            acc = fmaf(ww.x, v.x, acc); acc = fmaf(ww.y, v.y, acc);
            acc = fmaf(ww.z, v.z, acc); acc = fmaf(ww.w, v.w, acc);
        }
        gates[tid] = fmaxf(acc, 0.0f);   // reuse as hidden activations
    }
    __syncthreads();
    if (tid < 128) {
        float acc = b2[tid];
        const float4* w = (const float4*)(W2 + tid * 256);
        const float4* hq = (const float4*)gates;
#pragma unroll 8
        for (int k = 0; k < 64; ++k) {
            float4 ww = w[k]; float4 v = hq[k];
            acc = fmaf(ww.x, v.x, acc); acc = fmaf(ww.y, v.y, acc);
            acc = fmaf(ww.z, v.z, acc); acc = fmaf(ww.w, v.w, acc);
        }
        out[b * 128 + tid] = acc;
    }
}

extern "C" void kernel_launch(void* const* d_in, const int* in_sizes, int n_in,
                              void* d_out, int out_size, void* d_ws, size_t ws_size,
                              hipStream_t stream) {
    const float* x     = (const float*)d_in[0];   // [N,64]
    const int*   batch = (const int*)d_in[1];     // [N] sorted
    const float* W_ih  = (const float*)d_in[2];   // [256,128]
    const float* W_hh  = (const float*)d_in[3];   // [256,64]
    const float* b_ih  = (const float*)d_in[4];
    const float* b_hh  = (const float*)d_in[5];
    const float* W1    = (const float*)d_in[6];   // [256,128]
    const float* b1    = (const float*)d_in[7];
    const float* W2    = (const float*)d_in[8];   // [128,256]
    const float* b2    = (const float*)d_in[9];
    float* out = (float*)d_out;
    const int N = in_sizes[1];

    int* seg = (int*)d_ws;   // NB+1 ints

    seg_bounds_kernel<<<(N + 255) / 256, 256, 0, stream>>>(batch, seg, N);
    set2set_fused_kernel<<<NB, 512, 0, stream>>>(x, seg, W_ih, W_hh, b_ih, b_hh,
                                                 W1, b1, W2, b2, out);
}